// Round 7
// baseline (334.181 us; speedup 1.0000x reference)
//
#include <hip/hip_runtime.h>
#include <cstdint>
#include <cstddef>

#define BB   32
#define NN   1024
#define FIN  128
#define FOUT 128

typedef __attribute__((ext_vector_type(8))) short bf16x8;
typedef __attribute__((ext_vector_type(4))) float f32x4;

__device__ __forceinline__ unsigned int f2bf(float f) {
    union { float f; unsigned int u; } v; v.f = f;
    unsigned int u = v.u;
    return (u + 0x7FFFu + ((u >> 16) & 1u)) >> 16;   // RNE fp32 -> bf16
}
__device__ __forceinline__ unsigned int pack2(float a, float b) {
    return f2bf(a) | (f2bf(b) << 16);
}

// async global -> LDS DMA, 16 B per lane; LDS dst is wave-uniform base,
// HW scatters lane i to base + i*16 (m97/m104 semantics)
__device__ __forceinline__ void load_lds16(const void* g, void* l) {
    __builtin_amdgcn_global_load_lds(
        (const __attribute__((address_space(1))) unsigned int*)g,
        (__attribute__((address_space(3))) unsigned int*)l, 16, 0, 0);
}

// ---------------------------------------------------------------------------
// Kernel 1: Yt[b][o][m] = sum_f node[b][m][f] * W[o][f]  (bf16, [B][FOUT][NN])
// (multiply-verified; ~3 us)
// ---------------------------------------------------------------------------
__global__ __launch_bounds__(256) void y_kernel(const float* __restrict__ node,
                                                const float* __restrict__ W,
                                                unsigned short* __restrict__ Yt) {
    __shared__ unsigned short Wlds[128 * 136];
    __shared__ unsigned short Nlds[64 * 136];

    const int tid = threadIdx.x;
    const int bid = blockIdx.x;
    const int b   = bid >> 4;
    const int m0  = (bid & 15) * 64;

    #pragma unroll
    for (int i = 0; i < 16; ++i) {
        const int idx = i * 256 + tid;
        const int row = idx >> 5;
        const int c   = (idx & 31) * 4;
        float4 v = ((const float4*)W)[idx];
        uint2 p; p.x = pack2(v.x, v.y); p.y = pack2(v.z, v.w);
        *(uint2*)&Wlds[row * 136 + c] = p;
    }
    {
        const float* base = node + ((size_t)b * NN + m0) * FIN;
        #pragma unroll
        for (int i = 0; i < 8; ++i) {
            const int idx = i * 256 + tid;
            const int row = idx >> 5;
            const int c   = (idx & 31) * 4;
            float4 v = *(const float4*)(base + row * FIN + c);
            uint2 p; p.x = pack2(v.x, v.y); p.y = pack2(v.z, v.w);
            *(uint2*)&Nlds[row * 136 + c] = p;
        }
    }
    __syncthreads();

    const int w = tid >> 6, lane = tid & 63;
    const int wo = w * 32;
    const int lcol = lane & 15, lk = (lane >> 4) * 8;

    f32x4 acc[2][4] = {};
    #pragma unroll
    for (int kc = 0; kc < 4; ++kc) {
        const int kof = kc * 32 + lk;
        bf16x8 a[2], bb[4];
        #pragma unroll
        for (int mi = 0; mi < 2; ++mi)
            a[mi] = *(const bf16x8*)&Wlds[(wo + mi*16 + lcol) * 136 + kof];
        #pragma unroll
        for (int ni = 0; ni < 4; ++ni)
            bb[ni] = *(const bf16x8*)&Nlds[(ni*16 + lcol) * 136 + kof];
        #pragma unroll
        for (int mi = 0; mi < 2; ++mi)
            #pragma unroll
            for (int ni = 0; ni < 4; ++ni)
                acc[mi][ni] = __builtin_amdgcn_mfma_f32_16x16x32_bf16(
                    a[mi], bb[ni], acc[mi][ni], 0, 0, 0);
    }
    __syncthreads();

    unsigned short* Ylds = Wlds;
    const int rq = (lane >> 4) * 4;
    #pragma unroll
    for (int mi = 0; mi < 2; ++mi)
        #pragma unroll
        for (int ni = 0; ni < 4; ++ni)
            #pragma unroll
            for (int r = 0; r < 4; ++r) {
                const int o = wo + mi * 16 + rq + r;
                const int m = ni * 16 + lcol;
                Ylds[o * 72 + m] = (unsigned short)f2bf(acc[mi][ni][r]);
            }
    __syncthreads();

    {
        const int oq = tid >> 3, c = (tid & 7) * 8;
        #pragma unroll
        for (int j = 0; j < 4; ++j) {
            const int o = oq + 32 * j;
            uint4 v = *(const uint4*)&Ylds[o * 72 + c];
            *(uint4*)(Yt + ((size_t)b * FOUT + o) * NN + m0 + c) = v;
        }
    }
}

// ---------------------------------------------------------------------------
// Kernel 2 v9: BM=128 (208 MB traffic) + 3-buffer depth-2 prefetch.
// Round-6 post-mortem: effective CU-side byte rate tracks blocks/CU
// (r0/r3/r4 at 4+ blocks: 5.0-5.6 TB/s; r6 at 1 block: 3.1 TB/s) -> at
// grid 256 = 1 block/CU, depth-1 prefetch lets all 16 waves convoy on the
// per-step vmcnt+barrier. Fix: ring of 3 buffers (K_STEP=64, 144 KB LDS),
// prefetch 2 steps ahead, counted vmcnt(6) = 3 DMA/wave/step x 2 steps in
// flight (T4). Wait is issued ~2 full steps after its loads -> pre-satisfied;
// memory queues never drain. DMA layout / swizzle / fragment offsets /
// pack / rowsum / epilogue byte-identical to the passing r6 kernel.
// ---------------------------------------------------------------------------
#define ABYTES 32768                 // A: [128][64] fp32
#define BBYTES 16384                 // B: [128][64] bf16
#define BUFB   (ABYTES + BBYTES)     // 48 KB per buffer

__global__ __launch_bounds__(1024, 1) void gcn_kernel(const float* __restrict__ adj,
                                                      const unsigned short* __restrict__ Yt,
                                                      const float* __restrict__ bias,
                                                      float* __restrict__ out) {
    __shared__ __align__(16) char smem[3 * BUFB];    // 144 KB

    const int tid  = threadIdx.x;
    const int lane = tid & 63;
    const int w    = tid >> 6;                        // 0..15

    const int raw = blockIdx.x;                       // grid 256
    const int bid = (raw & 7) * 32 + (raw >> 3);      // XCD-contiguous, bijective
    const int b   = bid >> 3;
    const int n0  = (bid & 7) * 128;

    const int lcol = lane & 15, q = lane >> 4;
    const int wm = (w & 7) * 16;                      // row sixteenth (0..112)
    const int wn = (w >> 3) * 64;                     // col half     (0 / 64)

    // ---- DMA source/dest (source carries within-line chunk swizzle) ----
    // A: 128 rows x 64 fp32 = 32 KB/step = 32 instrs; wave w does j=0,1.
    const float* aSrc[2];
    char*        aDst[2];
    #pragma unroll
    for (int j = 0; j < 2; ++j) {
        const int i  = w * 2 + j;
        const int rA = i * 4 + (lane >> 4);
        const int c  = lane & 15;
        const int g  = (c & 8) | ((c & 7) ^ (rA & 7));
        aSrc[j] = adj + ((size_t)(b * NN + n0 + rA)) * NN + g * 4;
        aDst[j] = smem + i * 1024;
    }
    // B: 128 rows x 64 bf16 = 16 KB/step = 16 instrs; wave w does one.
    const unsigned short* bSrc;
    char* bDst;
    {
        const int o = w * 8 + (lane >> 3);
        const int c = lane & 7;
        const int g = c ^ (o & 7);
        bSrc = Yt + ((size_t)(b * FOUT + o)) * NN + g * 8;
        bDst = smem + ABYTES + w * 1024;
    }

    // ---- fragment read byte-offsets within a buffer (swizzle folded in) ----
    const int R = wm + lcol, keyR = R & 7;
    int offA[2][2], offB[2][4];
    #pragma unroll
    for (int kcl = 0; kcl < 2; ++kcl) {
        offA[kcl][0] = (R * 16 + kcl * 8 + ((2 * q)     ^ keyR)) * 16;
        offA[kcl][1] = (R * 16 + kcl * 8 + ((2 * q + 1) ^ keyR)) * 16;
        #pragma unroll
        for (int ni = 0; ni < 4; ++ni) {
            const int o = wn + ni * 16 + lcol;
            offB[kcl][ni] = ABYTES + (o * 8 + ((kcl * 4 + q) ^ (o & 7))) * 16;
        }
    }

    f32x4 acc[4] = {};
    float rsum = 0.f;

    #define STAGE(buf, s)                                                  \
        do {                                                               \
            load_lds16(aSrc[0] + (s) * 64, aDst[0] + (buf) * BUFB);        \
            load_lds16(aSrc[1] + (s) * 64, aDst[1] + (buf) * BUFB);        \
            load_lds16(bSrc    + (s) * 64, bDst    + (buf) * BUFB);        \
        } while (0)

    #define COMPUTE(buf)                                                   \
        do {                                                               \
            const char* base = smem + (buf) * BUFB;                        \
            _Pragma("unroll")                                              \
            for (int kcl = 0; kcl < 2; ++kcl) {                            \
                const float4 f0 = *(const float4*)(base + offA[kcl][0]);   \
                const float4 f1 = *(const float4*)(base + offA[kcl][1]);   \
                rsum += ((f0.x + f0.y) + (f0.z + f0.w))                    \
                      + ((f1.x + f1.y) + (f1.z + f1.w));                   \
                uint4 pk;                                                  \
                pk.x = pack2(f0.x, f0.y); pk.y = pack2(f0.z, f0.w);        \
                pk.z = pack2(f1.x, f1.y); pk.w = pack2(f1.z, f1.w);        \
                const bf16x8 a = *(const bf16x8*)&pk;                      \
                _Pragma("unroll")                                          \
                for (int ni = 0; ni < 4; ++ni) {                           \
                    const bf16x8 bbf = *(const bf16x8*)(base + offB[kcl][ni]); \
                    acc[ni] = __builtin_amdgcn_mfma_f32_16x16x32_bf16(     \
                        a, bbf, acc[ni], 0, 0, 0);                         \
                }                                                          \
            }                                                              \
        } while (0)

    // prologue: steps 0,1 -> bufs 0,1 (6 DMA/wave in flight)
    STAGE(0, 0);
    STAGE(1, 1);

    // 16 steps, fully unrolled: t literal -> buffer ring (t%3) and vmcnt
    // constants fold.  Depth-2: iter t stages step t+2 into buf (t+2)%3,
    // waits for step t (vmcnt(6): outstanding = t+1's 3 + t+2's 3; vmem
    // completion is in-order per wave, so <=6 outstanding => t's done).
    #pragma unroll
    for (int t = 0; t < 16; ++t) {
        if (t < 14) {
            STAGE((t + 2) % 3, t + 2);
            asm volatile("s_waitcnt vmcnt(6)" ::: "memory");
        } else if (t == 14) {
            asm volatile("s_waitcnt vmcnt(3)" ::: "memory");
        } else {
            asm volatile("s_waitcnt vmcnt(0)" ::: "memory");
        }
        __builtin_amdgcn_s_barrier();      // step t visible to all waves
        COMPUTE(t % 3);
        if (t < 15) __builtin_amdgcn_s_barrier();  // done reading buf t%3
                                           // before iter t+1 stages into it
    }
    #undef STAGE
    #undef COMPUTE

    // full row sums: lanes sharing lcol hold disjoint k-slices of row wm+lcol
    rsum += __shfl_xor(rsum, 16);
    rsum += __shfl_xor(rsum, 32);

    // D layout: col = lane&15 (o), row-in-tile = q*4 + r.
    // 1/rowsum for row wm+(rq+r): lane rq+r holds it (lcol = rq+r).
    const int rq = q * 4;
    float sc[4];
    #pragma unroll
    for (int r = 0; r < 4; ++r) sc[r] = 1.0f / __shfl(rsum, rq + r);

    float* outB = out + ((size_t)(b * NN + n0 + wm)) * FOUT;
    #pragma unroll
    for (int ni = 0; ni < 4; ++ni) {
        const float bc = bias[wn + ni * 16 + lcol];
        #pragma unroll
        for (int r = 0; r < 4; ++r) {
            float v = acc[ni][r] * sc[r] + bc;
            v = (v >= 0.f) ? v : 0.01f * v;
            outB[(size_t)(rq + r) * FOUT + wn + ni * 16 + lcol] = v;
        }
    }
}

extern "C" void kernel_launch(void* const* d_in, const int* in_sizes, int n_in,
                              void* d_out, int out_size, void* d_ws, size_t ws_size,
                              hipStream_t stream) {
    const float* node = (const float*)d_in[0];   // [32,1024,128]
    const float* adj  = (const float*)d_in[1];   // [32,1024,1024]
    const float* W    = (const float*)d_in[2];   // [128,128]
    const float* bias = (const float*)d_in[3];   // [128]
    float* out = (float*)d_out;                  // [32,1024,128] fp32
    unsigned short* Yt = (unsigned short*)d_ws;  // [32,128,1024] bf16 = 8 MiB

    hipLaunchKernelGGL(y_kernel,   dim3(512), dim3(256),  0, stream, node, W, Yt);
    hipLaunchKernelGGL(gcn_kernel, dim3(256), dim3(1024), 0, stream, adj, Yt, bias, out);
}

// Round 8
// 229.362 us; speedup vs baseline: 1.4570x; 1.4570x over previous
//
#include <hip/hip_runtime.h>
#include <cstdint>
#include <cstddef>

#define BB   32
#define NN   1024
#define FIN  128
#define FOUT 128

typedef __attribute__((ext_vector_type(8))) short bf16x8;
typedef __attribute__((ext_vector_type(4))) float f32x4;

__device__ __forceinline__ unsigned int f2bf(float f) {
    union { float f; unsigned int u; } v; v.f = f;
    unsigned int u = v.u;
    return (u + 0x7FFFu + ((u >> 16) & 1u)) >> 16;   // RNE fp32 -> bf16
}
__device__ __forceinline__ unsigned int pack2(float a, float b) {
    return f2bf(a) | (f2bf(b) << 16);
}

// async global -> LDS DMA, 16 B per lane; LDS dst is wave-uniform base,
// HW scatters lane i to base + i*16 (m97/m104 semantics)
__device__ __forceinline__ void load_lds16(const void* g, void* l) {
    __builtin_amdgcn_global_load_lds(
        (const __attribute__((address_space(1))) unsigned int*)g,
        (__attribute__((address_space(3))) unsigned int*)l, 16, 0, 0);
}

// ---------------------------------------------------------------------------
// Kernel 1: Yt[b][o][m] = sum_f node[b][m][f] * W[o][f]  (bf16, [B][FOUT][NN])
// (multiply-verified; ~3 us)
// ---------------------------------------------------------------------------
__global__ __launch_bounds__(256) void y_kernel(const float* __restrict__ node,
                                                const float* __restrict__ W,
                                                unsigned short* __restrict__ Yt) {
    __shared__ unsigned short Wlds[128 * 136];
    __shared__ unsigned short Nlds[64 * 136];

    const int tid = threadIdx.x;
    const int bid = blockIdx.x;
    const int b   = bid >> 4;
    const int m0  = (bid & 15) * 64;

    #pragma unroll
    for (int i = 0; i < 16; ++i) {
        const int idx = i * 256 + tid;
        const int row = idx >> 5;
        const int c   = (idx & 31) * 4;
        float4 v = ((const float4*)W)[idx];
        uint2 p; p.x = pack2(v.x, v.y); p.y = pack2(v.z, v.w);
        *(uint2*)&Wlds[row * 136 + c] = p;
    }
    {
        const float* base = node + ((size_t)b * NN + m0) * FIN;
        #pragma unroll
        for (int i = 0; i < 8; ++i) {
            const int idx = i * 256 + tid;
            const int row = idx >> 5;
            const int c   = (idx & 31) * 4;
            float4 v = *(const float4*)(base + row * FIN + c);
            uint2 p; p.x = pack2(v.x, v.y); p.y = pack2(v.z, v.w);
            *(uint2*)&Nlds[row * 136 + c] = p;
        }
    }
    __syncthreads();

    const int w = tid >> 6, lane = tid & 63;
    const int wo = w * 32;
    const int lcol = lane & 15, lk = (lane >> 4) * 8;

    f32x4 acc[2][4] = {};
    #pragma unroll
    for (int kc = 0; kc < 4; ++kc) {
        const int kof = kc * 32 + lk;
        bf16x8 a[2], bb[4];
        #pragma unroll
        for (int mi = 0; mi < 2; ++mi)
            a[mi] = *(const bf16x8*)&Wlds[(wo + mi*16 + lcol) * 136 + kof];
        #pragma unroll
        for (int ni = 0; ni < 4; ++ni)
            bb[ni] = *(const bf16x8*)&Nlds[(ni*16 + lcol) * 136 + kof];
        #pragma unroll
        for (int mi = 0; mi < 2; ++mi)
            #pragma unroll
            for (int ni = 0; ni < 4; ++ni)
                acc[mi][ni] = __builtin_amdgcn_mfma_f32_16x16x32_bf16(
                    a[mi], bb[ni], acc[mi][ni], 0, 0, 0);
    }
    __syncthreads();

    unsigned short* Ylds = Wlds;
    const int rq = (lane >> 4) * 4;
    #pragma unroll
    for (int mi = 0; mi < 2; ++mi)
        #pragma unroll
        for (int ni = 0; ni < 4; ++ni)
            #pragma unroll
            for (int r = 0; r < 4; ++r) {
                const int o = wo + mi * 16 + rq + r;
                const int m = ni * 16 + lcol;
                Ylds[o * 72 + m] = (unsigned short)f2bf(acc[mi][ni][r]);
            }
    __syncthreads();

    {
        const int oq = tid >> 3, c = (tid & 7) * 8;
        #pragma unroll
        for (int j = 0; j < 4; ++j) {
            const int o = oq + 32 * j;
            uint4 v = *(const uint4*)&Ylds[o * 72 + c];
            *(uint4*)(Yt + ((size_t)b * FOUT + o) * NN + m0 + c) = v;
        }
    }
}

// ---------------------------------------------------------------------------
// Kernel 2 v11: BM=128, 4-buffer ring, depth-2 prefetch, ONE barrier/step.
// Round-7 post-mortem: fully-unrolled depth-2 spilled (WRITE_SIZE 279 MB =
// ~1 KB/thread scratch). This version keeps the depth-2 window but with
// register discipline:
//  - K_STEP=32, buffer = A[128][32]f32 (16KB) + B[128][32]bf16 (8KB) = 24KB;
//    4 buffers = 96 KB LDS. Ring: iter t stages step t+2 into buf (t+2)%4,
//    which was last READ at iter t-2 ((t+2) === (t-2) mod 4); every wave
//    passed iter t-1's barrier, which is after its iter t-2 compute ->
//    staging is race-free with a SINGLE leading barrier per step.
//  - Staging roles: waves 0..7 issue the 16 A-loads (2 each), waves 8..11
//    the 8 B-loads (2 each), 12..15 none -> uniform 2 DMA/step/loader ->
//    one literal vmcnt(4) (= steps t+1,t+2 in flight) for everyone.
//  - Loop rolled, #pragma unroll 4 (ring indices fold); launch_bounds
//    (1024,4) -> VGPR cap 128, no 64-cap spill.
// In-flight window per load = one full step (~2400 cy BW-bound) > load
// latency -> vmcnt pre-satisfied, memory queue never drains.
// Swizzle (within-row XOR, both-sides), fragment k-indices, pack, rowsum,
// epilogue: same verified math as r6, re-derived for [128][32] step layout.
// ---------------------------------------------------------------------------
#define ABYTES 16384                 // A: [128][32] fp32
#define BBYTES 8192                  // B: [128][32] bf16
#define BUFB   (ABYTES + BBYTES)     // 24 KB per buffer

__global__ __launch_bounds__(1024, 4) void gcn_kernel(const float* __restrict__ adj,
                                                      const unsigned short* __restrict__ Yt,
                                                      const float* __restrict__ bias,
                                                      float* __restrict__ out) {
    __shared__ __align__(16) char smem[4 * BUFB];    // 96 KB

    const int tid  = threadIdx.x;
    const int lane = tid & 63;
    const int w    = tid >> 6;                        // 0..15

    const int raw = blockIdx.x;                       // grid 256
    const int bid = (raw & 7) * 32 + (raw >> 3);      // XCD-contiguous, bijective
    const int b   = bid >> 3;
    const int n0  = (bid & 7) * 128;

    const int lcol = lane & 15, q = lane >> 4;
    const int wm = (w & 7) * 16;                      // row sixteenth (0..112)
    const int wn = (w >> 3) * 64;                     // col half     (0 / 64)

    // ---- staging role (wave-uniform). src carries within-row XOR swizzle;
    //      LDS dst is linear (both-sides rule: reader applies same XOR). ----
    const char* src0 = nullptr; const char* src1 = nullptr;
    char* dst0 = nullptr; char* dst1 = nullptr;
    int sstride = 0;
    if (w < 8) {
        // A-loads: instr i = 2w+j covers rows i*8..i*8+7 (8 lanes/row,
        // 16B chunk c = lane&7, fetched chunk g = c ^ (row&7))
        const int i0 = 2 * w, i1 = 2 * w + 1;
        const int r0 = i0 * 8 + (lane >> 3), r1 = i1 * 8 + (lane >> 3);
        const int g0 = (lane & 7) ^ (r0 & 7), g1 = (lane & 7) ^ (r1 & 7);
        src0 = (const char*)(adj + ((size_t)(b * NN + n0 + r0)) * NN + g0 * 4);
        src1 = (const char*)(adj + ((size_t)(b * NN + n0 + r1)) * NN + g1 * 4);
        dst0 = smem + i0 * 1024;
        dst1 = smem + i1 * 1024;
        sstride = 128;                               // 32 fp32 per step
    } else if (w < 12) {
        // B-loads: instr j = 2(w-8)+jj covers rows j*16..j*16+15 (4 lanes/row,
        // 16B chunk c = lane&3, fetched g = c ^ (o&3))
        const int j0 = 2 * (w - 8), j1 = j0 + 1;
        const int o0 = j0 * 16 + (lane >> 2), o1 = j1 * 16 + (lane >> 2);
        const int g0 = (lane & 3) ^ (o0 & 3), g1 = (lane & 3) ^ (o1 & 3);
        src0 = (const char*)(Yt + ((size_t)(b * FOUT + o0)) * NN + g0 * 8);
        src1 = (const char*)(Yt + ((size_t)(b * FOUT + o1)) * NN + g1 * 8);
        dst0 = smem + ABYTES + j0 * 1024;
        dst1 = smem + ABYTES + j1 * 1024;
        sstride = 64;                                // 32 bf16 per step
    }

    // ---- fragment read byte-offsets within a buffer (swizzle folded in) ----
    // A row R: linear row*128B; reader wants global chunks 2q, 2q+1.
    const int R = wm + lcol, keyR = R & 7;
    const int offA0 = R * 128 + ((2 * q)     ^ keyR) * 16;
    const int offA1 = R * 128 + ((2 * q + 1) ^ keyR) * 16;
    // B row o: linear ABYTES + o*64B; reader wants global chunk q.
    int offB[4];
    #pragma unroll
    for (int ni = 0; ni < 4; ++ni) {
        const int o = wn + ni * 16 + lcol;
        offB[ni] = ABYTES + o * 64 + (q ^ (o & 3)) * 16;
    }

    f32x4 acc[4] = {};
    float rsum = 0.f;

    #define STAGE(buf, s)                                                   \
        do {                                                                \
            if (w < 12) {                                                   \
                load_lds16(src0 + (s) * sstride, dst0 + (buf) * BUFB);      \
                load_lds16(src1 + (s) * sstride, dst1 + (buf) * BUFB);      \
            }                                                               \
        } while (0)

    #define COMPUTE(buf)                                                    \
        do {                                                                \
            const char* base = smem + (buf) * BUFB;                         \
            const float4 f0 = *(const float4*)(base + offA0);               \
            const float4 f1 = *(const float4*)(base + offA1);               \
            rsum += ((f0.x + f0.y) + (f0.z + f0.w))                         \
                  + ((f1.x + f1.y) + (f1.z + f1.w));                        \
            uint4 pk;                                                       \
            pk.x = pack2(f0.x, f0.y); pk.y = pack2(f0.z, f0.w);             \
            pk.z = pack2(f1.x, f1.y); pk.w = pack2(f1.z, f1.w);             \
            const bf16x8 a = *(const bf16x8*)&pk;                           \
            _Pragma("unroll")                                               \
            for (int ni = 0; ni < 4; ++ni) {                                \
                const bf16x8 bbf = *(const bf16x8*)(base + offB[ni]);       \
                acc[ni] = __builtin_amdgcn_mfma_f32_16x16x32_bf16(          \
                    a, bbf, acc[ni], 0, 0, 0);                              \
            }                                                               \
        } while (0)

    // prologue: steps 0,1 -> bufs 0,1 (4 loads/loader-wave in flight)
    STAGE(0, 0);
    STAGE(1, 1);

    // steady state: stage t+2, wait step t (vmcnt(4): t+1,t+2 outstanding),
    // one barrier, compute. 28 iters; tail handles t=28..31.
    #pragma unroll 4
    for (int t = 0; t < 28; ++t) {
        STAGE((t + 2) & 3, t + 2);
        asm volatile("s_waitcnt vmcnt(4)" ::: "memory");
        __builtin_amdgcn_s_barrier();
        COMPUTE(t & 3);
    }
    // t=28
    STAGE(2, 30);
    asm volatile("s_waitcnt vmcnt(4)" ::: "memory");
    __builtin_amdgcn_s_barrier();
    COMPUTE(0);
    // t=29
    STAGE(3, 31);
    asm volatile("s_waitcnt vmcnt(4)" ::: "memory");
    __builtin_amdgcn_s_barrier();
    COMPUTE(1);
    // t=30
    asm volatile("s_waitcnt vmcnt(2)" ::: "memory");
    __builtin_amdgcn_s_barrier();
    COMPUTE(2);
    // t=31
    asm volatile("s_waitcnt vmcnt(0)" ::: "memory");
    __builtin_amdgcn_s_barrier();
    COMPUTE(3);
    #undef STAGE
    #undef COMPUTE

    // full row sums: lanes sharing lcol hold disjoint k-slices of row wm+lcol
    rsum += __shfl_xor(rsum, 16);
    rsum += __shfl_xor(rsum, 32);

    // D layout: col = lane&15 (o), row-in-tile = q*4 + r.
    // 1/rowsum for row wm+(rq+r): lane rq+r holds it (lcol = rq+r).
    const int rq = q * 4;
    float sc[4];
    #pragma unroll
    for (int r = 0; r < 4; ++r) sc[r] = 1.0f / __shfl(rsum, rq + r);

    float* outB = out + ((size_t)(b * NN + n0 + wm)) * FOUT;
    #pragma unroll
    for (int ni = 0; ni < 4; ++ni) {
        const float bc = bias[wn + ni * 16 + lcol];
        #pragma unroll
        for (int r = 0; r < 4; ++r) {
            float v = acc[ni][r] * sc[r] + bc;
            v = (v >= 0.f) ? v : 0.01f * v;
            outB[(size_t)(rq + r) * FOUT + wn + ni * 16 + lcol] = v;
        }
    }
}

extern "C" void kernel_launch(void* const* d_in, const int* in_sizes, int n_in,
                              void* d_out, int out_size, void* d_ws, size_t ws_size,
                              hipStream_t stream) {
    const float* node = (const float*)d_in[0];   // [32,1024,128]
    const float* adj  = (const float*)d_in[1];   // [32,1024,1024]
    const float* W    = (const float*)d_in[2];   // [128,128]
    const float* bias = (const float*)d_in[3];   // [128]
    float* out = (float*)d_out;                  // [32,1024,128] fp32
    unsigned short* Yt = (unsigned short*)d_ws;  // [32,128,1024] bf16 = 8 MiB

    hipLaunchKernelGGL(y_kernel,   dim3(512), dim3(256),  0, stream, node, W, Yt);
    hipLaunchKernelGGL(gcn_kernel, dim3(256), dim3(1024), 0, stream, adj, Yt, bias, out);
}

// Round 9
// 224.856 us; speedup vs baseline: 1.4862x; 1.0200x over previous
//
#include <hip/hip_runtime.h>
#include <cstdint>
#include <cstddef>

#define BB   32
#define NN   1024
#define FIN  128
#define FOUT 128

typedef __attribute__((ext_vector_type(8))) short bf16x8;
typedef __attribute__((ext_vector_type(4))) float f32x4;

__device__ __forceinline__ unsigned int f2bf(float f) {
    union { float f; unsigned int u; } v; v.f = f;
    unsigned int u = v.u;
    return (u + 0x7FFFu + ((u >> 16) & 1u)) >> 16;   // RNE fp32 -> bf16
}
__device__ __forceinline__ unsigned int pack2(float a, float b) {
    return f2bf(a) | (f2bf(b) << 16);
}

// async global -> LDS DMA, 16 B per lane; LDS dst is wave-uniform base,
// HW scatters lane i to base + i*16 (m97/m104 semantics)
__device__ __forceinline__ void load_lds16(const void* g, void* l) {
    __builtin_amdgcn_global_load_lds(
        (const __attribute__((address_space(1))) unsigned int*)g,
        (__attribute__((address_space(3))) unsigned int*)l, 16, 0, 0);
}

// ---------------------------------------------------------------------------
// Kernel 1: Yt[b][o][m] = sum_f node[b][m][f] * W[o][f]  (bf16, [B][FOUT][NN])
// (multiply-verified; ~3 us)
// ---------------------------------------------------------------------------
__global__ __launch_bounds__(256) void y_kernel(const float* __restrict__ node,
                                                const float* __restrict__ W,
                                                unsigned short* __restrict__ Yt) {
    __shared__ unsigned short Wlds[128 * 136];
    __shared__ unsigned short Nlds[64 * 136];

    const int tid = threadIdx.x;
    const int bid = blockIdx.x;
    const int b   = bid >> 4;
    const int m0  = (bid & 15) * 64;

    #pragma unroll
    for (int i = 0; i < 16; ++i) {
        const int idx = i * 256 + tid;
        const int row = idx >> 5;
        const int c   = (idx & 31) * 4;
        float4 v = ((const float4*)W)[idx];
        uint2 p; p.x = pack2(v.x, v.y); p.y = pack2(v.z, v.w);
        *(uint2*)&Wlds[row * 136 + c] = p;
    }
    {
        const float* base = node + ((size_t)b * NN + m0) * FIN;
        #pragma unroll
        for (int i = 0; i < 8; ++i) {
            const int idx = i * 256 + tid;
            const int row = idx >> 5;
            const int c   = (idx & 31) * 4;
            float4 v = *(const float4*)(base + row * FIN + c);
            uint2 p; p.x = pack2(v.x, v.y); p.y = pack2(v.z, v.w);
            *(uint2*)&Nlds[row * 136 + c] = p;
        }
    }
    __syncthreads();

    const int w = tid >> 6, lane = tid & 63;
    const int wo = w * 32;
    const int lcol = lane & 15, lk = (lane >> 4) * 8;

    f32x4 acc[2][4] = {};
    #pragma unroll
    for (int kc = 0; kc < 4; ++kc) {
        const int kof = kc * 32 + lk;
        bf16x8 a[2], bb[4];
        #pragma unroll
        for (int mi = 0; mi < 2; ++mi)
            a[mi] = *(const bf16x8*)&Wlds[(wo + mi*16 + lcol) * 136 + kof];
        #pragma unroll
        for (int ni = 0; ni < 4; ++ni)
            bb[ni] = *(const bf16x8*)&Nlds[(ni*16 + lcol) * 136 + kof];
        #pragma unroll
        for (int mi = 0; mi < 2; ++mi)
            #pragma unroll
            for (int ni = 0; ni < 4; ++ni)
                acc[mi][ni] = __builtin_amdgcn_mfma_f32_16x16x32_bf16(
                    a[mi], bb[ni], acc[mi][ni], 0, 0, 0);
    }
    __syncthreads();

    unsigned short* Ylds = Wlds;
    const int rq = (lane >> 4) * 4;
    #pragma unroll
    for (int mi = 0; mi < 2; ++mi)
        #pragma unroll
        for (int ni = 0; ni < 4; ++ni)
            #pragma unroll
            for (int r = 0; r < 4; ++r) {
                const int o = wo + mi * 16 + rq + r;
                const int m = ni * 16 + lcol;
                Ylds[o * 72 + m] = (unsigned short)f2bf(acc[mi][ni][r]);
            }
    __syncthreads();

    {
        const int oq = tid >> 3, c = (tid & 7) * 8;
        #pragma unroll
        for (int j = 0; j < 4; ++j) {
            const int o = oq + 32 * j;
            uint4 v = *(const uint4*)&Ylds[o * 72 + c];
            *(uint4*)(Yt + ((size_t)b * FOUT + o) * NN + m0 + c) = v;
        }
    }
}

// ---------------------------------------------------------------------------
// Kernel 2 v12: BM=64 — the traffic/block-TLP middle point.
// Cross-round law: effective CU-side delivery tracks blocks/CU (r0/r3/r4 at
// 4-6 blocks: 5.0-5.6 TB/s; r6/r8 at 1 block: ~3 TB/s regardless of
// pipeline depth); traffic tracks BM ( (1024/BM)*256KB Yt re-read + 4MB adj
// per batch ). BM=64: 256 MB total @ grid 512 = 2 blocks/CU -> predicted
// ~4.5-5 TB/s -> ~51 us.
// Structure = r6's verified skeleton re-parameterized (parameter change,
// not a new sync structure): 512 thr = 8 waves (4 row-groups x 2 col-halves,
// each wave 16 rows x 64 cols, acc[4]); K_STEP=64, double-buffer
// (A[64][64]f32 16KB + B[128][64]bf16 16KB = 32KB/buf, 64KB LDS -> exactly
// 2 blocks/CU); 4 DMA/wave/step -> counted vmcnt(4); same within-line XOR
// swizzle both-sides; fragment offsets identical to r6 (same buffer row
// layouts); pack / rowsum / epilogue byte-identical. Waves w and w+4
// compute the same row-group rsum independently (full k each) - no comms.
// ---------------------------------------------------------------------------
#define ABYTES 16384                 // A: [64][64] fp32
#define BBYTES 16384                 // B: [128][64] bf16
#define BUFB   (ABYTES + BBYTES)     // 32 KB per buffer

__global__ __launch_bounds__(512, 4) void gcn_kernel(const float* __restrict__ adj,
                                                     const unsigned short* __restrict__ Yt,
                                                     const float* __restrict__ bias,
                                                     float* __restrict__ out) {
    __shared__ __align__(16) char smem[2 * BUFB];    // 64 KB

    const int tid  = threadIdx.x;
    const int lane = tid & 63;
    const int w    = tid >> 6;                        // 0..7

    const int raw = blockIdx.x;                       // grid 512
    const int bid = (raw & 7) * 64 + (raw >> 3);      // XCD-contiguous, bijective
    const int b   = bid >> 4;
    const int n0  = (bid & 15) * 64;

    const int lcol = lane & 15, q = lane >> 4;
    const int wm = (w & 3) * 16;                      // row group (0..48)
    const int wn = (w >> 2) * 64;                     // col half  (0 / 64)

    // ---- DMA source/dest (source carries within-line chunk swizzle) ----
    // A: 64 rows x 64 fp32 = 16 KB/step = 16 instrs; wave w does i = 2w, 2w+1.
    //    instr i covers rows i*4..i*4+3; lane l: row i*4+(l>>4), 16B chunk
    //    c = l&15, fetched chunk g = (c&8) | ((c&7)^(row&7)).
    const float* aSrc[2];
    char*        aDst[2];
    #pragma unroll
    for (int j = 0; j < 2; ++j) {
        const int i  = w * 2 + j;
        const int rA = i * 4 + (lane >> 4);
        const int c  = lane & 15;
        const int g  = (c & 8) | ((c & 7) ^ (rA & 7));
        aSrc[j] = adj + ((size_t)(b * NN + n0 + rA)) * NN + g * 4;
        aDst[j] = smem + i * 1024;
    }
    // B: 128 rows x 64 bf16 = 16 KB/step = 16 instrs; wave w does j = 2w, 2w+1.
    //    instr j covers rows o = j*8..j*8+7; lane l: row j*8+(l>>3), chunk
    //    c = l&7, fetched g = c ^ (o&7).
    const unsigned short* bSrc[2];
    char* bDst[2];
    #pragma unroll
    for (int j = 0; j < 2; ++j) {
        const int jj = w * 2 + j;
        const int o  = jj * 8 + (lane >> 3);
        const int c  = lane & 7;
        const int g  = c ^ (o & 7);
        bSrc[j] = Yt + ((size_t)(b * FOUT + o)) * NN + g * 8;
        bDst[j] = smem + ABYTES + jj * 1024;
    }

    // ---- fragment read byte-offsets within a buffer (swizzle folded in) ----
    const int R = wm + lcol, keyR = R & 7;
    int offA[2][2], offB[2][4];
    #pragma unroll
    for (int kcl = 0; kcl < 2; ++kcl) {
        offA[kcl][0] = (R * 16 + kcl * 8 + ((2 * q)     ^ keyR)) * 16;
        offA[kcl][1] = (R * 16 + kcl * 8 + ((2 * q + 1) ^ keyR)) * 16;
        #pragma unroll
        for (int ni = 0; ni < 4; ++ni) {
            const int o = wn + ni * 16 + lcol;
            offB[kcl][ni] = ABYTES + (o * 8 + ((kcl * 4 + q) ^ (o & 7))) * 16;
        }
    }

    f32x4 acc[4] = {};
    float rsum = 0.f;

    #define STAGE(buf, s)                                                  \
        do {                                                               \
            load_lds16(aSrc[0] + (s) * 64, aDst[0] + (buf) * BUFB);        \
            load_lds16(aSrc[1] + (s) * 64, aDst[1] + (buf) * BUFB);        \
            load_lds16(bSrc[0] + (s) * 64, bDst[0] + (buf) * BUFB);        \
            load_lds16(bSrc[1] + (s) * 64, bDst[1] + (buf) * BUFB);        \
        } while (0)

    #define COMPUTE(buf)                                                   \
        do {                                                               \
            const char* base = smem + (buf) * BUFB;                        \
            _Pragma("unroll")                                              \
            for (int kcl = 0; kcl < 2; ++kcl) {                            \
                const float4 f0 = *(const float4*)(base + offA[kcl][0]);   \
                const float4 f1 = *(const float4*)(base + offA[kcl][1]);   \
                rsum += ((f0.x + f0.y) + (f0.z + f0.w))                    \
                      + ((f1.x + f1.y) + (f1.z + f1.w));                   \
                uint4 pk;                                                  \
                pk.x = pack2(f0.x, f0.y); pk.y = pack2(f0.z, f0.w);        \
                pk.z = pack2(f1.x, f1.y); pk.w = pack2(f1.z, f1.w);        \
                const bf16x8 a = *(const bf16x8*)&pk;                      \
                _Pragma("unroll")                                          \
                for (int ni = 0; ni < 4; ++ni) {                           \
                    const bf16x8 bbf = *(const bf16x8*)(base + offB[kcl][ni]); \
                    acc[ni] = __builtin_amdgcn_mfma_f32_16x16x32_bf16(     \
                        a, bbf, acc[ni], 0, 0, 0);                         \
                }                                                          \
            }                                                              \
        } while (0)

    // prologue: stage step 0 into buf0
    STAGE(0, 0);
    asm volatile("s_waitcnt vmcnt(0)" ::: "memory");
    __builtin_amdgcn_s_barrier();

    #pragma unroll 2
    for (int t = 0; t < 16; ++t) {
        const int cur = t & 1, nxt = cur ^ 1;
        if (t < 15) {
            STAGE(nxt, t + 1);                         // prefetch next step
            asm volatile("s_waitcnt vmcnt(4)" ::: "memory");  // step t's 4 done
        } else {
            asm volatile("s_waitcnt vmcnt(0)" ::: "memory");
        }
        __builtin_amdgcn_s_barrier();                  // step t visible to all
        COMPUTE(cur);
        if (t < 15) __builtin_amdgcn_s_barrier();      // done reading cur before
                                                       // next iter overwrites it
    }
    #undef STAGE
    #undef COMPUTE

    // full row sums: lanes sharing lcol hold disjoint k-slices of row wm+lcol
    rsum += __shfl_xor(rsum, 16);
    rsum += __shfl_xor(rsum, 32);

    // D layout: col = lane&15 (o), row-in-tile = q*4 + r.
    // 1/rowsum for row wm+(rq+r): lane rq+r holds it (lcol = rq+r).
    const int rq = q * 4;
    float sc[4];
    #pragma unroll
    for (int r = 0; r < 4; ++r) sc[r] = 1.0f / __shfl(rsum, rq + r);

    float* outB = out + ((size_t)(b * NN + n0 + wm)) * FOUT;
    #pragma unroll
    for (int ni = 0; ni < 4; ++ni) {
        const float bc = bias[wn + ni * 16 + lcol];
        #pragma unroll
        for (int r = 0; r < 4; ++r) {
            float v = acc[ni][r] * sc[r] + bc;
            v = (v >= 0.f) ? v : 0.01f * v;
            outB[(size_t)(rq + r) * FOUT + wn + ni * 16 + lcol] = v;
        }
    }
}

extern "C" void kernel_launch(void* const* d_in, const int* in_sizes, int n_in,
                              void* d_out, int out_size, void* d_ws, size_t ws_size,
                              hipStream_t stream) {
    const float* node = (const float*)d_in[0];   // [32,1024,128]
    const float* adj  = (const float*)d_in[1];   // [32,1024,1024]
    const float* W    = (const float*)d_in[2];   // [128,128]
    const float* bias = (const float*)d_in[3];   // [128]
    float* out = (float*)d_out;                  // [32,1024,128] fp32
    unsigned short* Yt = (unsigned short*)d_ws;  // [32,128,1024] bf16 = 8 MiB

    hipLaunchKernelGGL(y_kernel,   dim3(512), dim3(256), 0, stream, node, W, Yt);
    hipLaunchKernelGGL(gcn_kernel, dim3(512), dim3(512), 0, stream, adj, Yt, bias, out);
}